// Round 6
// baseline (185.732 us; speedup 1.0000x reference)
//
#include <hip/hip_runtime.h>
#include <stdint.h>

#define B_ 4
#define L_ 2048
#define D_ 1024
#define H_ 16
#define DK_ 64

typedef __attribute__((ext_vector_type(8))) short bf16x8;
typedef __attribute__((ext_vector_type(4))) float f32x4;
typedef unsigned short bfu;   // raw bf16 storage

#define MFMA(a, b, c) __builtin_amdgcn_mfma_f32_16x16x32_bf16((a), (b), (c), 0, 0, 0)

__device__ __forceinline__ unsigned short f2bf(float f) {
  union { float f; unsigned int u; } v; v.f = f;
  unsigned int u = v.u;
  return (unsigned short)((u + 0x7fffu + ((u >> 16) & 1u)) >> 16);  // RNE
}

__device__ __forceinline__ void gll16(const void* g, void* l) {
  __builtin_amdgcn_global_load_lds(
      (const __attribute__((address_space(1))) void*)g,
      (__attribute__((address_space(3))) void*)l, 16, 0, 0);
}

#define VMCNT(n_) asm volatile("s_waitcnt vmcnt(" #n_ ")" ::: "memory")
#define BARRIER() asm volatile("s_barrier" ::: "memory")

// ---------------- prep kernels ----------------

__global__ __launch_bounds__(256) void cast_x(const float* __restrict__ in,
                                              bfu* __restrict__ out, int n4) {
  int i = blockIdx.x * 256 + threadIdx.x;
  if (i >= n4) return;
  float4 v = ((const float4*)in)[i];
  ushort4 o;
  o.x = f2bf(v.x); o.y = f2bf(v.y); o.z = f2bf(v.z); o.w = f2bf(v.w);
  ((ushort4*)out)[i] = o;
}

// in[R][C] fp32 -> out[C][R] bf16
__global__ void transpose_cast(const float* __restrict__ in, bfu* __restrict__ out,
                               int R, int C) {
  __shared__ float tile[32][33];
  int c0 = blockIdx.x * 32, r0 = blockIdx.y * 32;
  int tx = threadIdx.x, ty = threadIdx.y;  // 32 x 8
#pragma unroll
  for (int i = ty; i < 32; i += 8)
    tile[i][tx] = in[(size_t)(r0 + i) * C + c0 + tx];
  __syncthreads();
#pragma unroll
  for (int i = ty; i < 32; i += 8)
    out[(size_t)(c0 + i) * R + r0 + tx] = f2bf(tile[tx][i]);
}

// ---------------- 256x256 8-phase BT GEMM (m201-faithful v2) ----------------
// C[M][N] = A[M][K] * Bt[N][K]^T. 512 threads = 8 waves (wm 2 x wn 4),
// per-wave output 128x64 (acc[8][4]). BK=64, double-buffered 128KB LDS.
// Per K-tile: 4 phases, each = [ds_read this phase's frags][stage 1 unit]
// [BAR][MFMA quadrant][counted VMCNT][BAR]. bfLO held in regs across the
// tile (p3 reads nothing). Waits: vmcnt(4) at end of p0/p1/p3 only.

template <int EPI>
__global__ __launch_bounds__(512, 2) void gemm8(
    const bfu* __restrict__ A, const bfu* __restrict__ Bt,
    const float* __restrict__ bias, bfu* __restrict__ Qg, bfu* __restrict__ Kg,
    bfu* __restrict__ Vtg, float* __restrict__ Out, int M, int N, int K) {
  __shared__ __align__(16) bfu LDSb[65536];  // A[2]@0 (32KB each), B[2]@32768
  const int tid = threadIdx.x;
  const int lane = tid & 63;
  const int w = tid >> 6;
  const int wm = w >> 2, wn = w & 3;
  const int l15 = lane & 15, l4 = lane >> 4;

  // XCD-bijective swizzle; m-fastest so consecutive swz share the B-panel
  const int nwg = gridDim.x;
  const int cpx = nwg >> 3;
  const int bid = (int)blockIdx.x;
  const int swz = (bid & 7) * cpx + (bid >> 3);
  const int m0 = (swz & 31) * 256;        // M = 8192 -> 32 m-tiles
  const int n0 = (swz >> 5) * 256;

  // stage unit ev of K-tile t (2 gll16/thread, 128 rows each):
  // ev0: A rows lo-halves {0-63,128-191}; ev1: B rows lo {0-31,64-95,...};
  // ev2: B rows hi (ev1+32); ev3: A rows hi (ev0+64)
#define STAGE(t_, ev_)                                                        \
  {                                                                           \
    const int c_ = (t_) & 1;                                                  \
    bfu* lb_ = ((ev_) == 0 || (ev_) == 3) ? (LDSb + c_ * 16384)               \
                                          : (LDSb + 32768 + c_ * 16384);      \
    const bfu* gs_ = ((ev_) == 0 || (ev_) == 3) ? A : Bt;                     \
    const int g0_ = ((ev_) == 0 || (ev_) == 3) ? m0 : n0;                     \
    _Pragma("unroll") for (int j_ = 0; j_ < 2; ++j_) {                        \
      int idx_ = j_ * 512 + tid;                                              \
      int r7_ = idx_ >> 3;                                                    \
      int row_;                                                               \
      if ((ev_) == 0) row_ = r7_ + ((r7_ >> 6) << 6);                         \
      else if ((ev_) == 3) row_ = 64 + r7_ + ((r7_ >> 6) << 6);               \
      else if ((ev_) == 1) row_ = r7_ + ((r7_ >> 5) << 5);                    \
      else row_ = 32 + r7_ + ((r7_ >> 5) << 5);                               \
      int c16_ = (idx_ & 7) ^ (row_ & 7);                                     \
      gll16(gs_ + (size_t)(g0_ + row_) * K + (t_) * 64 + c16_ * 8,            \
            (char*)lb_ + row_ * 128 + (idx_ & 7) * 16);                       \
    }                                                                         \
  }

  f32x4 acc[8][4] = {};
  bf16x8 af[4][2], bfLO[2][2], bfHI[2][2];

  auto lda = [&](int c, int half) {
    const char* base = (const char*)(LDSb + c * 16384);
#pragma unroll
    for (int mi = 0; mi < 4; ++mi)
#pragma unroll
      for (int kk = 0; kk < 2; ++kk) {
        int row = wm * 128 + half * 64 + mi * 16 + l15;
        int ch = (kk * 4 + l4) ^ (row & 7);
        af[mi][kk] = *(const bf16x8*)(base + row * 128 + ch * 16);
      }
  };
  auto ldb = [&](int c, int half, bf16x8 (*dst)[2]) {
    const char* base = (const char*)(LDSb + 32768 + c * 16384);
#pragma unroll
    for (int ni = 0; ni < 2; ++ni)
#pragma unroll
      for (int kk = 0; kk < 2; ++kk) {
        int row = wn * 64 + half * 32 + ni * 16 + l15;
        int ch = (kk * 4 + l4) ^ (row & 7);
        dst[ni][kk] = *(const bf16x8*)(base + row * 128 + ch * 16);
      }
  };

#define MM(mo_, no_, bfX_)                                                    \
  __builtin_amdgcn_s_setprio(1);                                              \
  _Pragma("unroll") for (int mi_ = 0; mi_ < 4; ++mi_)                         \
  _Pragma("unroll") for (int ni_ = 0; ni_ < 2; ++ni_)                         \
  _Pragma("unroll") for (int kk_ = 0; kk_ < 2; ++kk_)                         \
    acc[(mo_) + mi_][(no_) + ni_] =                                           \
        MFMA(af[mi_][kk_], bfX_[ni_][kk_], acc[(mo_) + mi_][(no_) + ni_]);    \
  __builtin_amdgcn_s_setprio(0);

  // ---- prologue: stage all 4 units of K-tile 0
  STAGE(0, 0); STAGE(0, 1); STAGE(0, 2); STAGE(0, 3);
  VMCNT(4);   // U_Alo(0), U_Blo(0) landed; U_Bhi(0), U_Ahi(0) in flight
  BARRIER();

  const int NT = K >> 6;
  for (int t = 0; t < NT - 1; ++t) {
    const int c = t & 1, tn = t + 1;
    // phase 0: q(lo,lo)
    lda(c, 0); ldb(c, 0, bfLO);   // 12 ds_reads
    STAGE(tn, 0);                 // U_Alo(t+1)
    BARRIER();
    MM(0, 0, bfLO);
    VMCNT(4); BARRIER();          // drains U_Bhi(t)
    // phase 1: q(lo,hi)
    ldb(c, 1, bfHI);
    STAGE(tn, 1);                 // U_Blo(t+1)
    BARRIER();
    MM(0, 2, bfHI);
    VMCNT(4); BARRIER();          // drains U_Ahi(t)
    // phase 2: q(hi,hi)
    lda(c, 1);
    STAGE(tn, 2);                 // U_Bhi(t+1)
    BARRIER();
    MM(4, 2, bfHI);
    BARRIER();                    // no vmcnt
    // phase 3: q(hi,lo) — no ds_reads (bfLO live)
    STAGE(tn, 3);                 // U_Ahi(t+1)
    BARRIER();
    MM(4, 0, bfLO);
    VMCNT(4); BARRIER();          // drains U_Alo(t+1), U_Blo(t+1)
  }
  {  // peeled last K-tile
    const int c = (NT - 1) & 1;
    lda(c, 0); ldb(c, 0, bfLO);
    MM(0, 0, bfLO);
    VMCNT(2); BARRIER();          // U_Bhi landed
    ldb(c, 1, bfHI);
    MM(0, 2, bfHI);
    VMCNT(0); BARRIER();          // U_Ahi landed
    lda(c, 1);
    MM(4, 2, bfHI);
    MM(4, 0, bfLO);
  }

  // ---- epilogue: C/D layout col = lane&15, row = (lane>>4)*4 + reg
  if (EPI == 1) {
#pragma unroll
    for (int ni = 0; ni < 4; ++ni) {
      int gn = n0 + wn * 64 + ni * 16 + l15;
      float bv = bias[gn];
#pragma unroll
      for (int mi = 0; mi < 8; ++mi)
#pragma unroll
        for (int rg = 0; rg < 4; ++rg) {
          int gm = m0 + wm * 128 + mi * 16 + l4 * 4 + rg;
          Out[(size_t)gm * N + gn] = acc[mi][ni][rg] + bv;
        }
    }
  } else {
    const int sec = n0 >> 10;  // 0..3 Q, 4..7 K, 8..11 V (256-wide n tiles)
    if (sec < 2) {
      bfu* dst = (sec == 0) ? Qg : Kg;
      const float scale = (sec == 0) ? 0.18033688011112042f : 1.0f;  // log2e/8
#pragma unroll
      for (int ni = 0; ni < 4; ++ni) {
        int gn = n0 + wn * 64 + ni * 16 + l15;
        int rem = gn & 1023;
        int hh = rem >> 6, dk = rem & 63;
        float bv = bias[gn];
#pragma unroll
        for (int mi = 0; mi < 8; ++mi)
#pragma unroll
          for (int rg = 0; rg < 4; ++rg) {
            int gm = m0 + wm * 128 + mi * 16 + l4 * 4 + rg;
            int bb = gm >> 11, ll = gm & 2047;
            dst[(((size_t)(bb * H_ + hh)) * L_ + ll) * DK_ + dk] =
                f2bf((acc[mi][ni][rg] + bv) * scale);
          }
      }
    } else {
      // V: transpose via LDS with sigma^-1 kv-permutation, contiguous stores
      __syncthreads();  // K-loop LDS reads done everywhere
#pragma unroll
      for (int ni = 0; ni < 4; ++ni) {
        int n_local = wn * 64 + ni * 16 + l15;
        int gn = n0 + n_local;
        float bv = bias[gn];
        int swzn = (n_local & 7) << 4;
#pragma unroll
        for (int mi = 0; mi < 8; ++mi) {
          int m_base = wm * 128 + mi * 16 + l4 * 4;
          int k6 = m_base & 63;
          int p0 = (m_base & ~63) |
                   ((k6 & 32) | (((k6 >> 2) & 3) << 3) | (((k6 >> 4) & 1) << 2));
          float v0 = acc[mi][ni][0] + bv, v1 = acc[mi][ni][1] + bv;
          float v2 = acc[mi][ni][2] + bv, v3 = acc[mi][ni][3] + bv;
          uint32_t w01, w23;
          asm("v_cvt_pk_bf16_f32 %0, %1, %2" : "=v"(w01) : "v"(v0), "v"(v1));
          asm("v_cvt_pk_bf16_f32 %0, %1, %2" : "=v"(w23) : "v"(v2), "v"(v3));
          *(uint32_t*)((char*)LDSb + n_local * 512 + ((2 * p0) ^ swzn)) = w01;
          *(uint32_t*)((char*)LDSb + n_local * 512 + ((2 * p0 + 4) ^ swzn)) = w23;
        }
      }
      __syncthreads();
      int n = tid >> 1;
      int cb = (tid & 1) * 16;
      int gnn = n0 + n;
      int hh = (gnn >> 6) & 15, dk = gnn & 63;
      size_t rowbase =
          (((size_t)((m0 >> 11) * H_ + hh)) * DK_ + dk) * L_ + (m0 & 2047);
#pragma unroll
      for (int j = 0; j < 16; ++j) {
        int ch = cb + j;
        bf16x8 vv = *(const bf16x8*)((char*)LDSb + n * 512 +
                                     ((ch * 16) ^ ((n & 7) << 4)));
        *(bf16x8*)(Vtg + rowbase + ch * 8) = vv;
      }
    }
  }
#undef STAGE
#undef MM
}

// ---------------- flash attention v3 (causal) ----------------
// 512 blocks; xcd = hid&7, 8 bh per XCD (K/V L2 locality). Block handles
// 128-row q-superblocks {p, 15-p} (34 KV tiles, perfect balance). 4 waves;
// wave owns 32 q rows (2 x 16). Q loaded directly to registers (no Q LDS).
// S^T = mfma(K,Q): lane owns softmax stats of one q-row per half. V stored
// sigma-permuted so packed P words ARE the PV A-fragment (no cross-lane).

__global__ __launch_bounds__(256, 3) void attn(const bfu* __restrict__ Qg,
                                               const bfu* __restrict__ Kg,
                                               const bfu* __restrict__ Vtg,
                                               bfu* __restrict__ Ao) {
  __shared__ __align__(16) bfu Ks[2 * 64 * 64];
  __shared__ __align__(16) bfu Vs[2 * 64 * 64];

  const int tid = threadIdx.x;
  const int lane = tid & 63;
  const int w = tid >> 6;
  const int l15 = lane & 15, l4 = lane >> 4;

  const int hid = blockIdx.x;            // 512 blocks
  const int xcd = hid & 7, slot = hid >> 3;
  const int bh = xcd * 8 + (slot >> 3);  // 8 bh per XCD
  const int p = slot & 7;
  const int b = bh >> 4, h = bh & 15;

  for (int seg = 0; seg < 2; ++seg) {
    const int qb = (seg == 0) ? p : 15 - p;   // 128-row superblock
    const int q0 = qb * 128;
    const int nt = 2 * qb + 2;
    const int q0w = q0 + w * 32;              // wave's first q row

    // ---- Q fragments straight from global (Qg pre-scaled by log2e/8)
    bf16x8 qf[2][2];
#pragma unroll
    for (int mi = 0; mi < 2; ++mi)
#pragma unroll
      for (int kk = 0; kk < 2; ++kk)
        qf[mi][kk] = *(const bf16x8*)(
            Qg + ((size_t)bh * L_ + q0w + mi * 16 + l15) * DK_ + kk * 32 + l4 * 8);

    // ---- stage KV tile 0 (buffer 0)
#pragma unroll
    for (int i = 0; i < 2; ++i) {
      int lb = i * 256 + tid;
      int r = lb >> 3, c16 = (lb & 7) ^ (r & 7);
      gll16(Kg + ((size_t)bh * L_ + r) * DK_ + c16 * 8, (char*)Ks + lb * 16);
      gll16(Vtg + ((size_t)bh * DK_ + r) * L_ + c16 * 8, (char*)Vs + lb * 16);
    }
    VMCNT(0);
    BARRIER();

    f32x4 acco[2][4] = {};          // [half][d-block]; row q = l4*4+rg
    float m[2] = {-1e30f, -1e30f};  // per-lane: q = l15 (per half)
    float l[2] = {0.f, 0.f};

    for (int t = 0; t < nt; ++t) {
      const int cur = t & 1;
      const int kv0 = t * 64;
      const char* Kc = (const char*)Ks + cur * 8192;
      const char* Vc = (const char*)Vs + cur * 8192;

      if (t + 1 < nt) {
        const int nb = (t + 1) & 1, nkv = (t + 1) * 64;
#pragma unroll
        for (int i = 0; i < 2; ++i) {
          int lb = i * 256 + tid;
          int r = lb >> 3, c16 = (lb & 7) ^ (r & 7);
          gll16(Kg + ((size_t)bh * L_ + nkv + r) * DK_ + c16 * 8,
                (char*)Ks + nb * 8192 + lb * 16);
          gll16(Vtg + ((size_t)bh * DK_ + r) * L_ + nkv + c16 * 8,
                (char*)Vs + nb * 8192 + lb * 16);
        }
        VMCNT(4);
      } else {
        VMCNT(0);
      }
      BARRIER();

      if (kv0 <= q0w + 31) {  // wave has unmasked rows in this tile
        // ---- S^T = K Q^T : s[mi][ni][rg] = S^T[kv=ni*16+l4*4+rg][q=l15]
        f32x4 s[2][4] = {};
        __builtin_amdgcn_s_setprio(1);
#pragma unroll
        for (int kk = 0; kk < 2; ++kk)
#pragma unroll
          for (int ni = 0; ni < 4; ++ni) {
            int r = ni * 16 + l15;
            int ch = (kk * 4 + l4) ^ (r & 7);
            bf16x8 kf = *(const bf16x8*)(Kc + r * 128 + ch * 16);
#pragma unroll
            for (int mi = 0; mi < 2; ++mi)
              s[mi][ni] = MFMA(kf, qf[mi][kk], s[mi][ni]);
          }
        __builtin_amdgcn_s_setprio(0);

        if (kv0 + 63 > q0w) {  // diagonal band: mask kv > q
#pragma unroll
          for (int mi = 0; mi < 2; ++mi) {
            int qg_ = q0w + mi * 16 + l15;
#pragma unroll
            for (int ni = 0; ni < 4; ++ni) {
              int kvg = kv0 + ni * 16 + l4 * 4;
#pragma unroll
              for (int rg = 0; rg < 4; ++rg)
                if (kvg + rg > qg_) s[mi][ni][rg] = -1e30f;
            }
          }
        }

        // ---- row max + defer-max rescale
        float mx[2];
#pragma unroll
        for (int mi = 0; mi < 2; ++mi) {
          float v = fmaxf(fmaxf(fmaxf(s[mi][0][0], s[mi][0][1]),
                                fmaxf(s[mi][0][2], s[mi][0][3])),
                          fmaxf(fmaxf(s[mi][1][0], s[mi][1][1]),
                                fmaxf(s[mi][1][2], s[mi][1][3])));
          v = fmaxf(v, fmaxf(fmaxf(fmaxf(s[mi][2][0], s[mi][2][1]),
                                   fmaxf(s[mi][2][2], s[mi][2][3])),
                             fmaxf(fmaxf(s[mi][3][0], s[mi][3][1]),
                                   fmaxf(s[mi][3][2], s[mi][3][3]))));
          v = fmaxf(v, __shfl_xor(v, 16));
          v = fmaxf(v, __shfl_xor(v, 32));
          mx[mi] = v;
        }
        float grow = fmaxf(mx[0] - m[0], mx[1] - m[1]);
        if (__any(grow > 11.0f)) {
#pragma unroll
          for (int mi = 0; mi < 2; ++mi) {
            float mn = fmaxf(m[mi], mx[mi]);
            float sc = __builtin_amdgcn_exp2f(m[mi] - mn);
            m[mi] = mn;
            l[mi] *= sc;
#pragma unroll
            for (int rg = 0; rg < 4; ++rg) {
              float scq = __shfl(sc, l4 * 4 + rg);
              acco[mi][0][rg] *= scq; acco[mi][1][rg] *= scq;
              acco[mi][2][rg] *= scq; acco[mi][3][rg] *= scq;
            }
          }
        }

        // ---- P = exp2(S^T - m), pack bf16 pairs (kv ascending)
        uint32_t pk[2][4][2];
#pragma unroll
        for (int mi = 0; mi < 2; ++mi)
#pragma unroll
          for (int ni = 0; ni < 4; ++ni) {
            float p0 = __builtin_amdgcn_exp2f(s[mi][ni][0] - m[mi]);
            float p1 = __builtin_amdgcn_exp2f(s[mi][ni][1] - m[mi]);
            float p2 = __builtin_amdgcn_exp2f(s[mi][ni][2] - m[mi]);
            float p3 = __builtin_amdgcn_exp2f(s[mi][ni][3] - m[mi]);
            l[mi] += (p0 + p1) + (p2 + p3);
            asm("v_cvt_pk_bf16_f32 %0, %1, %2" : "=v"(pk[mi][ni][0]) : "v"(p0), "v"(p1));
            asm("v_cvt_pk_bf16_f32 %0, %1, %2" : "=v"(pk[mi][ni][1]) : "v"(p2), "v"(p3));
          }

        // ---- O += P V : pk words ARE the A-frag (V kv-cols pre-permuted)
        __builtin_amdgcn_s_setprio(1);
#pragma unroll
        for (int kk = 0; kk < 2; ++kk) {
          union { uint32_t wd[4]; bf16x8 v; } u[2];
#pragma unroll
          for (int mi = 0; mi < 2; ++mi) {
            u[mi].wd[0] = pk[mi][2 * kk][0];
            u[mi].wd[1] = pk[mi][2 * kk][1];
            u[mi].wd[2] = pk[mi][2 * kk + 1][0];
            u[mi].wd[3] = pk[mi][2 * kk + 1][1];
          }
#pragma unroll
          for (int ni = 0; ni < 4; ++ni) {
            int r = ni * 16 + l15;
            int ch = (kk * 4 + l4) ^ (r & 7);
            bf16x8 vf = *(const bf16x8*)(Vc + r * 128 + ch * 16);
#pragma unroll
            for (int mi = 0; mi < 2; ++mi)
              acco[mi][ni] = MFMA(u[mi].v, vf, acco[mi][ni]);
          }
        }
        __builtin_amdgcn_s_setprio(0);
      }  // active wave

      BARRIER();  // all waves done with buf[cur]
    }

    // ---- epilogue
#pragma unroll
    for (int mi = 0; mi < 2; ++mi) {
      float ls = l[mi];
      ls += __shfl_xor(ls, 16);
      ls += __shfl_xor(ls, 32);
      float linv = 1.0f / ls;
#pragma unroll
      for (int rg = 0; rg < 4; ++rg) {
        float lq = __shfl(linv, l4 * 4 + rg);
        int q = q0w + mi * 16 + l4 * 4 + rg;
#pragma unroll
        for (int ni = 0; ni < 4; ++ni) {
          int d = ni * 16 + l15;
          Ao[((size_t)b * L_ + q) * D_ + h * DK_ + d] = f2bf(acco[mi][ni][rg] * lq);
        }
      }
    }
  }  // seg
}

// ---------------- launch ----------------

extern "C" void kernel_launch(void* const* d_in, const int* in_sizes, int n_in,
                              void* d_out, int out_size, void* d_ws, size_t ws_size,
                              hipStream_t stream) {
  const float* x = (const float*)d_in[0];
  const float* W_qkv = (const float*)d_in[1];
  const float* b_qkv = (const float*)d_in[2];
  const float* W_out = (const float*)d_in[3];
  const float* b_out = (const float*)d_in[4];
  float* out = (float*)d_out;

  char* ws = (char*)d_ws;
  bfu* xb     = (bfu*)(ws);                    // 8192*1024*2   = 16,777,216
  bfu* Wqkv_t = (bfu*)(ws + 16777216);         // 3072*1024*2   =  6,291,456
  bfu* Wout_t = (bfu*)(ws + 23068672);         // 1024*1024*2   =  2,097,152
  bfu* Qg     = (bfu*)(ws + 25165824);         // 16,777,216
  bfu* Kg     = (bfu*)(ws + 41943040);         // 16,777,216
  bfu* Vtg    = (bfu*)(ws + 58720256);         // 16,777,216
  bfu* Ao     = (bfu*)(ws + 75497472);         // 16,777,216  (total ~92.3 MB)

  cast_x<<<8192, 256, 0, stream>>>(x, xb, 2097152);
  transpose_cast<<<dim3(96, 32), dim3(32, 8), 0, stream>>>(W_qkv, Wqkv_t, 1024, 3072);
  transpose_cast<<<dim3(32, 32), dim3(32, 8), 0, stream>>>(W_out, Wout_t, 1024, 1024);

  gemm8<0><<<384, 512, 0, stream>>>(xb, Wqkv_t, b_qkv, Qg, Kg, Vtg, nullptr,
                                    8192, 3072, 1024);
  attn<<<512, 256, 0, stream>>>(Qg, Kg, Vtg, Ao);
  gemm8<1><<<128, 512, 0, stream>>>(Ao, Wout_t, b_out, nullptr, nullptr, nullptr,
                                    out, 8192, 1024, 1024);
}

// Round 7
// 179.928 us; speedup vs baseline: 1.0323x; 1.0323x over previous
//
#include <hip/hip_runtime.h>
#include <stdint.h>

#define B_ 4
#define L_ 2048
#define D_ 1024
#define H_ 16
#define DK_ 64

typedef __attribute__((ext_vector_type(8))) short bf16x8;
typedef __attribute__((ext_vector_type(4))) float f32x4;
typedef unsigned short bfu;   // raw bf16 storage

#define MFMA(a, b, c) __builtin_amdgcn_mfma_f32_16x16x32_bf16((a), (b), (c), 0, 0, 0)

__device__ __forceinline__ unsigned short f2bf(float f) {
  union { float f; unsigned int u; } v; v.f = f;
  unsigned int u = v.u;
  return (unsigned short)((u + 0x7fffu + ((u >> 16) & 1u)) >> 16);  // RNE
}

__device__ __forceinline__ void gll16(const void* g, void* l) {
  __builtin_amdgcn_global_load_lds(
      (const __attribute__((address_space(1))) void*)g,
      (__attribute__((address_space(3))) void*)l, 16, 0, 0);
}

#define VMCNT(n_) asm volatile("s_waitcnt vmcnt(" #n_ ")" ::: "memory")
#define BARRIER() asm volatile("s_barrier" ::: "memory")

template <int N> __device__ __forceinline__ void vmwait() {
  static_assert(N >= 0 && N <= 8, "vmcnt range");
  if constexpr (N == 0) VMCNT(0);
  else if constexpr (N == 1) VMCNT(1);
  else if constexpr (N == 2) VMCNT(2);
  else if constexpr (N == 3) VMCNT(3);
  else if constexpr (N == 4) VMCNT(4);
  else if constexpr (N == 5) VMCNT(5);
  else if constexpr (N == 6) VMCNT(6);
  else if constexpr (N == 7) VMCNT(7);
  else VMCNT(8);
}

// ---------------- prep kernels ----------------

__global__ __launch_bounds__(256) void cast_x(const float* __restrict__ in,
                                              bfu* __restrict__ out, int n4) {
  int i = blockIdx.x * 256 + threadIdx.x;
  if (i >= n4) return;
  float4 v = ((const float4*)in)[i];
  ushort4 o;
  o.x = f2bf(v.x); o.y = f2bf(v.y); o.z = f2bf(v.z); o.w = f2bf(v.w);
  ((ushort4*)out)[i] = o;
}

// in[R][C] fp32 -> out[C][R] bf16
__global__ void transpose_cast(const float* __restrict__ in, bfu* __restrict__ out,
                               int R, int C) {
  __shared__ float tile[32][33];
  int c0 = blockIdx.x * 32, r0 = blockIdx.y * 32;
  int tx = threadIdx.x, ty = threadIdx.y;  // 32 x 8
#pragma unroll
  for (int i = ty; i < 32; i += 8)
    tile[i][tx] = in[(size_t)(r0 + i) * C + c0 + tx];
  __syncthreads();
#pragma unroll
  for (int i = ty; i < 32; i += 8)
    out[(size_t)(c0 + i) * R + r0 + tx] = f2bf(tile[tx][i]);
}

// ---------------- BMxBN 4-phase BT GEMM, 3-phase vmcnt slack ----------------
// C[M][N] = A[M][K] * Bt[N][K]^T. 512 threads = 8 waves (wm 2 x wn 4),
// per-wave output (BM/2)x(BN/4). BK=64, double-buffered LDS.
// Stage units: LO = A-lo + B-lo (staged p0), B-hi (p1), A-hi (p2).
// Each unit is consumed exactly 4 phases after issue; the wait that retires
// it runs 3 phases after issue (vmcnt<HA+LO>/<LO+HB>/none/<HB+HA>).
// One barrier per phase. EPI 0 (BM=BN=256): scatter Q (scaled log2e/8), K,
// and V (via LDS sigma^-1-permuted transpose). EPI 1: fp32 out += bias.

template <int EPI, int BM, int BN>
__global__ __launch_bounds__(512, 2) void gemm8(
    const bfu* __restrict__ A, const bfu* __restrict__ Bt,
    const float* __restrict__ bias, bfu* __restrict__ Qg, bfu* __restrict__ Kg,
    bfu* __restrict__ Vtg, float* __restrict__ Out, int M, int N, int K) {
  __shared__ __align__(16) bfu LDSb[(BM + BN) * 128];  // A[2] then B[2]
  constexpr int MH = BM / 64;    // A frag count per half
  constexpr int NH = BN / 128;   // B frag count per half
  constexpr int HA = BM / 128;   // loads/thread for an A half-unit
  constexpr int HB = BN / 128;   // loads/thread for a B half-unit
  constexpr int LO = HA + HB;

  const int tid = threadIdx.x;
  const int lane = tid & 63;
  const int w = tid >> 6;
  const int wm = w >> 2, wn = w & 3;
  const int l15 = lane & 15, l4 = lane >> 4;

  // XCD-bijective swizzle; m-fastest so consecutive swz share the B-panel
  const int nwg = gridDim.x;
  const int cpx = nwg >> 3;
  const int bid = (int)blockIdx.x;
  const int swz = (bid & 7) * cpx + (bid >> 3);
  const int MT = M / BM;
  const int m0 = (swz % MT) * BM;
  const int n0 = (swz / MT) * BN;

  auto stageA = [&](int t, int half) {
    bfu* lb = LDSb + (t & 1) * (BM * 64);
#pragma unroll
    for (int j = 0; j < HA; ++j) {
      int idx = j * 512 + tid;
      int u = idx >> 3;  // [0, BM/2)
      int row = half * (BM / 4) + (u & (BM / 4 - 1)) + (u / (BM / 4)) * (BM / 2);
      int c16 = (idx & 7) ^ (row & 7);
      gll16(A + (size_t)(m0 + row) * K + t * 64 + c16 * 8,
            (char*)lb + row * 128 + (idx & 7) * 16);
    }
  };
  auto stageB = [&](int t, int half) {
    bfu* lb = LDSb + 2 * BM * 64 + (t & 1) * (BN * 64);
#pragma unroll
    for (int j = 0; j < HB; ++j) {
      int idx = j * 512 + tid;
      int u = idx >> 3;  // [0, BN/2)
      int row = half * (BN / 8) + (u & (BN / 8 - 1)) + (u / (BN / 8)) * (BN / 4);
      int c16 = (idx & 7) ^ (row & 7);
      gll16(Bt + (size_t)(n0 + row) * K + t * 64 + c16 * 8,
            (char*)lb + row * 128 + (idx & 7) * 16);
    }
  };

  f32x4 acc[2 * MH][2 * NH] = {};
  bf16x8 af[MH][2], bfLO[NH][2], bfHI[NH][2];

  auto lda = [&](int c, int half) {
    const char* base = (const char*)(LDSb + c * (BM * 64));
#pragma unroll
    for (int mi = 0; mi < MH; ++mi)
#pragma unroll
      for (int kk = 0; kk < 2; ++kk) {
        int row = wm * (BM / 2) + half * (BM / 4) + mi * 16 + l15;
        int ch = (kk * 4 + l4) ^ (row & 7);
        af[mi][kk] = *(const bf16x8*)(base + row * 128 + ch * 16);
      }
  };
  auto ldb = [&](int c, int half, bf16x8 (&dst)[NH][2]) {
    const char* base = (const char*)(LDSb + 2 * BM * 64 + c * (BN * 64));
#pragma unroll
    for (int ni = 0; ni < NH; ++ni)
#pragma unroll
      for (int kk = 0; kk < 2; ++kk) {
        int row = wn * (BN / 4) + half * (BN / 8) + ni * 16 + l15;
        int ch = (kk * 4 + l4) ^ (row & 7);
        dst[ni][kk] = *(const bf16x8*)(base + row * 128 + ch * 16);
      }
  };
  auto mm = [&](int mo, int no, bf16x8 (&bx)[NH][2]) {
    __builtin_amdgcn_s_setprio(1);
#pragma unroll
    for (int mi = 0; mi < MH; ++mi)
#pragma unroll
      for (int ni = 0; ni < NH; ++ni)
#pragma unroll
        for (int kk = 0; kk < 2; ++kk)
          acc[mo + mi][no + ni] = MFMA(af[mi][kk], bx[ni][kk], acc[mo + mi][no + ni]);
    __builtin_amdgcn_s_setprio(0);
  };

  // ---- prologue: stage tile 0 units in order LO(A-lo,B-lo), B-hi, A-hi
  stageA(0, 0); stageB(0, 0); stageB(0, 1); stageA(0, 1);
  vmwait<HB + HA>();   // retires LO(0); B-hi(0), A-hi(0) stay in flight
  BARRIER();

  const int NT = K >> 6;
  for (int t = 0; t < NT - 1; ++t) {
    const int c = t & 1, tn = t + 1;
    // p0: quadrant (lo,lo)
    lda(c, 0); ldb(c, 0, bfLO);
    stageA(tn, 0); stageB(tn, 0);      // LO(t+1)
    mm(0, 0, bfLO);
    vmwait<HA + LO>(); BARRIER();      // retires BHI(t) [staged p1(t-1)]
    // p1: quadrant (lo,hi)
    ldb(c, 1, bfHI);
    stageB(tn, 1);                     // BHI(t+1)
    mm(0, NH, bfHI);
    vmwait<LO + HB>(); BARRIER();      // retires AHI(t) [staged p2(t-1)]
    // p2: quadrant (hi,hi)
    lda(c, 1);
    stageA(tn, 1);                     // AHI(t+1)
    mm(MH, NH, bfHI);
    BARRIER();                         // no wait
    // p3: quadrant (hi,lo) — no ds_reads (bfLO live)
    mm(MH, 0, bfLO);
    vmwait<HB + HA>(); BARRIER();      // retires LO(t+1) [staged p0(t)]
  }
  {  // peeled last K-tile: outstanding on entry = {BHI(t), AHI(t)}
    const int c = (NT - 1) & 1;
    lda(c, 0); ldb(c, 0, bfLO);
    mm(0, 0, bfLO);
    vmwait<HA>(); BARRIER();           // retires BHI(t)
    ldb(c, 1, bfHI);
    mm(0, NH, bfHI);
    vmwait<0>(); BARRIER();            // retires AHI(t)
    lda(c, 1);
    mm(MH, NH, bfHI);
    mm(MH, 0, bfLO);
  }

  // ---- epilogue: C/D layout col = lane&15, row = (lane>>4)*4 + reg
  if constexpr (EPI == 1) {
#pragma unroll
    for (int ni = 0; ni < 2 * NH; ++ni) {
      int gn = n0 + wn * (BN / 4) + ni * 16 + l15;
      float bv = bias[gn];
#pragma unroll
      for (int mi = 0; mi < 2 * MH; ++mi)
#pragma unroll
        for (int rg = 0; rg < 4; ++rg) {
          int gm = m0 + wm * (BM / 2) + mi * 16 + l4 * 4 + rg;
          Out[(size_t)gm * N + gn] = acc[mi][ni][rg] + bv;
        }
    }
  } else {
    const int sec = n0 >> 10;  // 0..3 Q, 4..7 K, 8..11 V (256-wide n tiles)
    if (sec < 2) {
      bfu* dst = (sec == 0) ? Qg : Kg;
      const float scale = (sec == 0) ? 0.18033688011112042f : 1.0f;  // log2e/8
#pragma unroll
      for (int ni = 0; ni < 2 * NH; ++ni) {
        int gn = n0 + wn * (BN / 4) + ni * 16 + l15;
        int rem = gn & 1023;
        int hh = rem >> 6, dk = rem & 63;
        float bv = bias[gn];
#pragma unroll
        for (int mi = 0; mi < 2 * MH; ++mi)
#pragma unroll
          for (int rg = 0; rg < 4; ++rg) {
            int gm = m0 + wm * (BM / 2) + mi * 16 + l4 * 4 + rg;
            int bb = gm >> 11, ll = gm & 2047;
            dst[(((size_t)(bb * H_ + hh)) * L_ + ll) * DK_ + dk] =
                f2bf((acc[mi][ni][rg] + bv) * scale);
          }
      }
    } else {
      // V: transpose via LDS with sigma^-1 kv-permutation, contiguous stores
      __syncthreads();  // K-loop LDS reads done everywhere
#pragma unroll
      for (int ni = 0; ni < 2 * NH; ++ni) {
        int n_local = wn * (BN / 4) + ni * 16 + l15;
        int gn = n0 + n_local;
        float bv = bias[gn];
        int swzn = (n_local & 7) << 4;
#pragma unroll
        for (int mi = 0; mi < 2 * MH; ++mi) {
          int m_base = wm * (BM / 2) + mi * 16 + l4 * 4;
          int k6 = m_base & 63;
          int p0 = (m_base & ~63) |
                   ((k6 & 32) | (((k6 >> 2) & 3) << 3) | (((k6 >> 4) & 1) << 2));
          float v0 = acc[mi][ni][0] + bv, v1 = acc[mi][ni][1] + bv;
          float v2 = acc[mi][ni][2] + bv, v3 = acc[mi][ni][3] + bv;
          uint32_t w01, w23;
          asm("v_cvt_pk_bf16_f32 %0, %1, %2" : "=v"(w01) : "v"(v0), "v"(v1));
          asm("v_cvt_pk_bf16_f32 %0, %1, %2" : "=v"(w23) : "v"(v2), "v"(v3));
          *(uint32_t*)((char*)LDSb + n_local * 512 + ((2 * p0) ^ swzn)) = w01;
          *(uint32_t*)((char*)LDSb + n_local * 512 + ((2 * p0 + 4) ^ swzn)) = w23;
        }
      }
      __syncthreads();
      int n = tid >> 1;
      int cb = (tid & 1) * 16;
      int gnn = n0 + n;
      int hh = (gnn >> 6) & 15, dk = gnn & 63;
      size_t rowbase =
          (((size_t)((m0 >> 11) * H_ + hh)) * DK_ + dk) * L_ + (m0 & 2047);
#pragma unroll
      for (int j = 0; j < 16; ++j) {
        int ch = cb + j;
        bf16x8 vv = *(const bf16x8*)((char*)LDSb + n * 512 +
                                     ((ch * 16) ^ ((n & 7) << 4)));
        *(bf16x8*)(Vtg + rowbase + ch * 8) = vv;
      }
    }
  }
}

// ---------------- flash attention v3 (causal) ----------------
// 512 blocks; xcd = hid&7, 8 bh per XCD (K/V L2 locality). Block handles
// 128-row q-superblocks {p, 15-p} (34 KV tiles, perfect balance). 4 waves;
// wave owns 32 q rows (2 x 16). Q loaded directly to registers (no Q LDS).
// S^T = mfma(K,Q): lane owns softmax stats of one q-row per half. V stored
// sigma-permuted so packed P words ARE the PV A-fragment (no cross-lane).

__global__ __launch_bounds__(256, 3) void attn(const bfu* __restrict__ Qg,
                                               const bfu* __restrict__ Kg,
                                               const bfu* __restrict__ Vtg,
                                               bfu* __restrict__ Ao) {
  __shared__ __align__(16) bfu Ks[2 * 64 * 64];
  __shared__ __align__(16) bfu Vs[2 * 64 * 64];

  const int tid = threadIdx.x;
  const int lane = tid & 63;
  const int w = tid >> 6;
  const int l15 = lane & 15, l4 = lane >> 4;

  const int hid = blockIdx.x;            // 512 blocks
  const int xcd = hid & 7, slot = hid >> 3;
  const int bh = xcd * 8 + (slot >> 3);  // 8 bh per XCD
  const int p = slot & 7;
  const int b = bh >> 4, h = bh & 15;

  for (int seg = 0; seg < 2; ++seg) {
    const int qb = (seg == 0) ? p : 15 - p;   // 128-row superblock
    const int q0 = qb * 128;
    const int nt = 2 * qb + 2;
    const int q0w = q0 + w * 32;              // wave's first q row

    // ---- Q fragments straight from global (Qg pre-scaled by log2e/8)
    bf16x8 qf[2][2];
#pragma unroll
    for (int mi = 0; mi < 2; ++mi)
#pragma unroll
      for (int kk = 0; kk < 2; ++kk)
        qf[mi][kk] = *(const bf16x8*)(
            Qg + ((size_t)bh * L_ + q0w + mi * 16 + l15) * DK_ + kk * 32 + l4 * 8);

    // ---- stage KV tile 0 (buffer 0)
#pragma unroll
    for (int i = 0; i < 2; ++i) {
      int lb = i * 256 + tid;
      int r = lb >> 3, c16 = (lb & 7) ^ (r & 7);
      gll16(Kg + ((size_t)bh * L_ + r) * DK_ + c16 * 8, (char*)Ks + lb * 16);
      gll16(Vtg + ((size_t)bh * DK_ + r) * L_ + c16 * 8, (char*)Vs + lb * 16);
    }
    VMCNT(0);
    BARRIER();

    f32x4 acco[2][4] = {};          // [half][d-block]; row q = l4*4+rg
    float m[2] = {-1e30f, -1e30f};  // per-lane: q = l15 (per half)
    float l[2] = {0.f, 0.f};

    for (int t = 0; t < nt; ++t) {
      const int cur = t & 1;
      const int kv0 = t * 64;
      const char* Kc = (const char*)Ks + cur * 8192;
      const char* Vc = (const char*)Vs + cur * 8192;

      if (t + 1 < nt) {
        const int nb = (t + 1) & 1, nkv = (t + 1) * 64;
#pragma unroll
        for (int i = 0; i < 2; ++i) {
          int lb = i * 256 + tid;
          int r = lb >> 3, c16 = (lb & 7) ^ (r & 7);
          gll16(Kg + ((size_t)bh * L_ + nkv + r) * DK_ + c16 * 8,
                (char*)Ks + nb * 8192 + lb * 16);
          gll16(Vtg + ((size_t)bh * DK_ + r) * L_ + nkv + c16 * 8,
                (char*)Vs + nb * 8192 + lb * 16);
        }
        VMCNT(4);
      } else {
        VMCNT(0);
      }
      BARRIER();

      if (kv0 <= q0w + 31) {  // wave has unmasked rows in this tile
        // ---- S^T = K Q^T : s[mi][ni][rg] = S^T[kv=ni*16+l4*4+rg][q=l15]
        f32x4 s[2][4] = {};
        __builtin_amdgcn_s_setprio(1);
#pragma unroll
        for (int kk = 0; kk < 2; ++kk)
#pragma unroll
          for (int ni = 0; ni < 4; ++ni) {
            int r = ni * 16 + l15;
            int ch = (kk * 4 + l4) ^ (r & 7);
            bf16x8 kf = *(const bf16x8*)(Kc + r * 128 + ch * 16);
#pragma unroll
            for (int mi = 0; mi < 2; ++mi)
              s[mi][ni] = MFMA(kf, qf[mi][kk], s[mi][ni]);
          }
        __builtin_amdgcn_s_setprio(0);

        if (kv0 + 63 > q0w) {  // diagonal band: mask kv > q
#pragma unroll
          for (int mi = 0; mi < 2; ++mi) {
            int qg_ = q0w + mi * 16 + l15;
#pragma unroll
            for (int ni = 0; ni < 4; ++ni) {
              int kvg = kv0 + ni * 16 + l4 * 4;
#pragma unroll
              for (int rg = 0; rg < 4; ++rg)
                if (kvg + rg > qg_) s[mi][ni][rg] = -1e30f;
            }
          }
        }

        // ---- row max + defer-max rescale
        float mx[2];
#pragma unroll
        for (int mi = 0; mi < 2; ++mi) {
          float v = fmaxf(fmaxf(fmaxf(s[mi][0][0], s[mi][0][1]),
                                fmaxf(s[mi][0][2], s[mi][0][3])),
                          fmaxf(fmaxf(s[mi][1][0], s[mi][1][1]),
                                fmaxf(s[mi][1][2], s[mi][1][3])));
          v = fmaxf(v, fmaxf(fmaxf(fmaxf(s[mi][2][0], s[mi][2][1]),
                                   fmaxf(s[mi][2][2], s[mi][2][3])),
                             fmaxf(fmaxf(s[mi][3][0], s[mi][3][1]),
                                   fmaxf(s[mi][3][2], s[mi][3][3]))));
          v = fmaxf(v, __shfl_xor(v, 16));
          v = fmaxf(v, __shfl_xor(v, 32));
          mx[mi] = v;
        }
        float grow = fmaxf(mx[0] - m[0], mx[1] - m[1]);
        if (__any(grow > 11.0f)) {
#pragma unroll
          for (int mi = 0; mi < 2; ++mi) {
            float mn = fmaxf(m[mi], mx[mi]);
            float sc = __builtin_amdgcn_exp2f(m[mi] - mn);
            m[mi] = mn;
            l[mi] *= sc;
#pragma unroll
            for (int rg = 0; rg < 4; ++rg) {
              float scq = __shfl(sc, l4 * 4 + rg);
              acco[mi][0][rg] *= scq; acco[mi][1][rg] *= scq;
              acco[mi][2][rg] *= scq; acco[mi][3][rg] *= scq;
            }
          }
        }

        // ---- P = exp2(S^T - m), pack bf16 pairs (kv ascending)
        uint32_t pk[2][4][2];
#pragma unroll
        for (int mi = 0; mi < 2; ++mi)
#pragma unroll
          for (int ni = 0; ni < 4; ++ni) {
            float p0 = __builtin_amdgcn_exp2f(s[mi][ni][0] - m[mi]);
            float p1 = __builtin_amdgcn_exp2f(s[mi][ni][1] - m[mi]);
            float p2 = __builtin_amdgcn_exp2f(s[mi][ni][2] - m[mi]);
            float p3 = __builtin_amdgcn_exp2f(s[mi][ni][3] - m[mi]);
            l[mi] += (p0 + p1) + (p2 + p3);
            asm("v_cvt_pk_bf16_f32 %0, %1, %2" : "=v"(pk[mi][ni][0]) : "v"(p0), "v"(p1));
            asm("v_cvt_pk_bf16_f32 %0, %1, %2" : "=v"(pk[mi][ni][1]) : "v"(p2), "v"(p3));
          }

        // ---- O += P V : pk words ARE the A-frag (V kv-cols pre-permuted)
        __builtin_amdgcn_s_setprio(1);
#pragma unroll
        for (int kk = 0; kk < 2; ++kk) {
          union { uint32_t wd[4]; bf16x8 v; } u[2];
#pragma unroll
          for (int mi = 0; mi < 2; ++mi) {
            u[mi].wd[0] = pk[mi][2 * kk][0];
            u[mi].wd[1] = pk[mi][2 * kk][1];
            u[mi].wd[2] = pk[mi][2 * kk + 1][0];
            u[mi].wd[3] = pk[mi][2 * kk + 1][1];
          }
#pragma unroll
          for (int ni = 0; ni < 4; ++ni) {
            int r = ni * 16 + l15;
            int ch = (kk * 4 + l4) ^ (r & 7);
            bf16x8 vf = *(const bf16x8*)(Vc + r * 128 + ch * 16);
#pragma unroll
            for (int mi = 0; mi < 2; ++mi)
              acco[mi][ni] = MFMA(u[mi].v, vf, acco[mi][ni]);
          }
        }
        __builtin_amdgcn_s_setprio(0);
      }  // active wave

      BARRIER();  // all waves done with buf[cur]
    }

    // ---- epilogue
#pragma unroll
    for (int mi = 0; mi < 2; ++mi) {
      float ls = l[mi];
      ls += __shfl_xor(ls, 16);
      ls += __shfl_xor(ls, 32);
      float linv = 1.0f / ls;
#pragma unroll
      for (int rg = 0; rg < 4; ++rg) {
        float lq = __shfl(linv, l4 * 4 + rg);
        int q = q0w + mi * 16 + l4 * 4 + rg;
#pragma unroll
        for (int ni = 0; ni < 4; ++ni) {
          int d = ni * 16 + l15;
          Ao[((size_t)b * L_ + q) * D_ + h * DK_ + d] = f2bf(acco[mi][ni][rg] * lq);
        }
      }
    }
  }  // seg
}

// ---------------- launch ----------------

extern "C" void kernel_launch(void* const* d_in, const int* in_sizes, int n_in,
                              void* d_out, int out_size, void* d_ws, size_t ws_size,
                              hipStream_t stream) {
  const float* x = (const float*)d_in[0];
  const float* W_qkv = (const float*)d_in[1];
  const float* b_qkv = (const float*)d_in[2];
  const float* W_out = (const float*)d_in[3];
  const float* b_out = (const float*)d_in[4];
  float* out = (float*)d_out;

  char* ws = (char*)d_ws;
  bfu* xb     = (bfu*)(ws);                    // 8192*1024*2   = 16,777,216
  bfu* Wqkv_t = (bfu*)(ws + 16777216);         // 3072*1024*2   =  6,291,456
  bfu* Wout_t = (bfu*)(ws + 23068672);         // 1024*1024*2   =  2,097,152
  bfu* Qg     = (bfu*)(ws + 25165824);         // 16,777,216
  bfu* Kg     = (bfu*)(ws + 41943040);         // 16,777,216
  bfu* Vtg    = (bfu*)(ws + 58720256);         // 16,777,216
  bfu* Ao     = (bfu*)(ws + 75497472);         // 16,777,216  (total ~92.3 MB)

  cast_x<<<8192, 256, 0, stream>>>(x, xb, 2097152);
  transpose_cast<<<dim3(96, 32), dim3(32, 8), 0, stream>>>(W_qkv, Wqkv_t, 1024, 3072);
  transpose_cast<<<dim3(32, 32), dim3(32, 8), 0, stream>>>(W_out, Wout_t, 1024, 1024);

  gemm8<0, 256, 256><<<384, 512, 0, stream>>>(xb, Wqkv_t, b_qkv, Qg, Kg, Vtg,
                                              nullptr, 8192, 3072, 1024);
  attn<<<512, 256, 0, stream>>>(Qg, Kg, Vtg, Ao);
  gemm8<1, 128, 256><<<256, 512, 0, stream>>>(Ao, Wout_t, b_out, nullptr, nullptr,
                                              nullptr, out, 8192, 1024, 1024);
}